// Round 2
// baseline (368.101 us; speedup 1.0000x reference)
//
#include <hip/hip_runtime.h>
#include <hip/hip_bf16.h>

// Problem: B=32, T=2048, D=1024 (fp32 in/out)
// out = [context (B*D), attention_weights (B*T)]  (fp32, concatenated)
#define BB 32
#define TT 2048
#define DD 1024
#define TCHUNK 32               // rows per wave
#define NC (TT / TCHUNK)        // 64 chunks per batch
#define WPB 4                   // waves per block (256 threads)
#define BLOCKS_PER_B (NC / WPB) // 16

// Workspace layout (fp32):
//   scores : B*T           (65536)
//   pm     : B*NC          (2048)
//   pl     : B*NC          (2048)
//   pctx   : B*NC*D        (2097152)
// total ~8.4 MiB

__global__ __launch_bounds__(256) void attn_pass1(
    const float* __restrict__ query,
    const float* __restrict__ values,
    float* __restrict__ ws) {
    float* scores = ws;
    float* pm = ws + BB * TT;
    float* pl = pm + BB * NC;
    float* pctx = pl + BB * NC;

    const int tid  = threadIdx.x;
    const int lane = tid & 63;
    const int wave = tid >> 6;
    const int b     = blockIdx.x / BLOCKS_PER_B;
    const int chunk = (blockIdx.x % BLOCKS_PER_B) * WPB + wave;
    const int t0    = chunk * TCHUNK;

    // Query fragment: lane covers d in {g*256 + 4*lane + j : g=0..3, j=0..3}
    const float4* qrow = (const float4*)(query + (size_t)b * DD);
    float qf[16];
#pragma unroll
    for (int g = 0; g < 4; g++) {
        float4 q4 = qrow[g * 64 + lane];
        qf[4 * g + 0] = q4.x; qf[4 * g + 1] = q4.y;
        qf[4 * g + 2] = q4.z; qf[4 * g + 3] = q4.w;
    }

    const float4* vbase = (const float4*)(values + ((size_t)b * TT + t0) * DD);
    // row stride = D/4 = 256 float4

    float m = -INFINITY, l = 0.f;
    float ctx[16];
#pragma unroll
    for (int k = 0; k < 16; k++) ctx[k] = 0.f;

    float4 cur[4];
#pragma unroll
    for (int g = 0; g < 4; g++) cur[g] = vbase[g * 64 + lane];

    for (int r = 0; r < TCHUNK; r++) {
        float4 nxt[4];
        const bool have_next = (r + 1 < TCHUNK);
        if (have_next) {
#pragma unroll
            for (int g = 0; g < 4; g++)
                nxt[g] = vbase[(size_t)(r + 1) * 256 + g * 64 + lane];
        }
        float vf[16];
#pragma unroll
        for (int g = 0; g < 4; g++) {
            vf[4 * g + 0] = cur[g].x; vf[4 * g + 1] = cur[g].y;
            vf[4 * g + 2] = cur[g].z; vf[4 * g + 3] = cur[g].w;
        }

        float s = 0.f;
#pragma unroll
        for (int k = 0; k < 16; k++) s = fmaf(qf[k], vf[k], s);
#pragma unroll
        for (int off = 32; off >= 1; off >>= 1) s += __shfl_xor(s, off, 64);

        // online softmax update (s, m wave-uniform -> uniform branch)
        if (s <= m) {
            float p = __expf(s - m);
            l += p;
#pragma unroll
            for (int k = 0; k < 16; k++) ctx[k] = fmaf(p, vf[k], ctx[k]);
        } else {
            float corr = __expf(m - s);   // exp(-inf)=0 on first row
            m = s;
            l = fmaf(l, corr, 1.f);
#pragma unroll
            for (int k = 0; k < 16; k++) ctx[k] = fmaf(ctx[k], corr, vf[k]);
        }
        if (lane == 0) scores[(size_t)b * TT + t0 + r] = s;
        if (have_next) {
#pragma unroll
            for (int g = 0; g < 4; g++) cur[g] = nxt[g];
        }
    }

    const int ci = b * NC + chunk;
    if (lane == 0) { pm[ci] = m; pl[ci] = l; }
    float4* pc = (float4*)(pctx + (size_t)ci * DD);
#pragma unroll
    for (int g = 0; g < 4; g++)
        pc[g * 64 + lane] = make_float4(ctx[4 * g + 0], ctx[4 * g + 1],
                                        ctx[4 * g + 2], ctx[4 * g + 3]);
}

__global__ __launch_bounds__(256) void attn_pass2(
    const float* __restrict__ ws,
    float* __restrict__ out) {
    const float* scores = ws;
    const float* pm = ws + BB * TT;
    const float* pl = pm + BB * NC;
    const float* pctx = pl + BB * NC;

    const int tid   = threadIdx.x;
    const int b     = blockIdx.x >> 2;
    const int slice = blockIdx.x & 3;

    __shared__ float s_e[NC];
    __shared__ float s_M, s_L;
    if (tid < 64) {  // wave 0: reduce the 64 chunk partials
        float mi = pm[b * NC + tid];
        float li = pl[b * NC + tid];
        float M = mi;
#pragma unroll
        for (int off = 32; off >= 1; off >>= 1) M = fmaxf(M, __shfl_xor(M, off, 64));
        float e  = __expf(mi - M);
        float lw = li * e;
#pragma unroll
        for (int off = 32; off >= 1; off >>= 1) lw += __shfl_xor(lw, off, 64);
        s_e[tid] = e;
        if (tid == 0) { s_M = M; s_L = lw; }
    }
    __syncthreads();
    const float M  = s_M;
    const float rL = 1.0f / s_L;

    // context slice: d = slice*256 + tid
    const int d = slice * 256 + tid;
    const float* base = pctx + (size_t)b * NC * DD + d;
    float acc = 0.f;
#pragma unroll 8
    for (int i = 0; i < NC; i++) acc = fmaf(base[(size_t)i * DD], s_e[i], acc);
    out[(size_t)b * DD + d] = acc * rL;

    // weights: t = slice*512 + k*256 + tid
    float* wout = out + BB * DD;
#pragma unroll
    for (int k = 0; k < 2; k++) {
        int t = slice * 512 + k * 256 + tid;
        float w = __expf(scores[(size_t)b * TT + t] - M) * rL;
        wout[(size_t)b * TT + t] = w;
    }
}

extern "C" void kernel_launch(void* const* d_in, const int* in_sizes, int n_in,
                              void* d_out, int out_size, void* d_ws, size_t ws_size,
                              hipStream_t stream) {
    const float* query  = (const float*)d_in[0];
    const float* values = (const float*)d_in[1];
    float* ws = (float*)d_ws;
    float* out = (float*)d_out;

    attn_pass1<<<dim3(BB * BLOCKS_PER_B), dim3(256), 0, stream>>>(query, values, ws);
    attn_pass2<<<dim3(BB * 4), dim3(256), 0, stream>>>(ws, out);
}

// Round 3
// 367.696 us; speedup vs baseline: 1.0011x; 1.0011x over previous
//
#include <hip/hip_runtime.h>
#include <hip/hip_bf16.h>

// Problem: B=32, T=2048, D=1024 (fp32 in/out)
// out = [context (B*D), attention_weights (B*T)]  (fp32, concatenated)
#define BB 32
#define TT 2048
#define DD 1024
#define TCHUNK 32               // rows per wave
#define NC (TT / TCHUNK)        // 64 chunks per batch
#define WPB 4                   // waves per block (256 threads)
#define BLOCKS_PER_B (NC / WPB) // 16

// Workspace layout (fp32):
//   scores : B*T           (65536)
//   pm     : B*NC          (2048)
//   pl     : B*NC          (2048)
//   pctx   : B*NC*D        (2097152)
// total ~8.4 MiB

__global__ __launch_bounds__(256) void attn_pass1(
    const float* __restrict__ query,
    const float* __restrict__ values,
    float* __restrict__ ws) {
    float* scores = ws;
    float* pm = ws + BB * TT;
    float* pl = pm + BB * NC;
    float* pctx = pl + BB * NC;

    const int tid  = threadIdx.x;
    const int lane = tid & 63;
    const int wave = tid >> 6;
    const int b     = blockIdx.x / BLOCKS_PER_B;
    const int chunk = (blockIdx.x % BLOCKS_PER_B) * WPB + wave;
    const int t0    = chunk * TCHUNK;

    // Query fragment: lane covers d in {g*256 + 4*lane + j : g=0..3, j=0..3}
    const float4* qrow = (const float4*)(query + (size_t)b * DD);
    float qf[16];
#pragma unroll
    for (int g = 0; g < 4; g++) {
        float4 q4 = qrow[g * 64 + lane];
        qf[4 * g + 0] = q4.x; qf[4 * g + 1] = q4.y;
        qf[4 * g + 2] = q4.z; qf[4 * g + 3] = q4.w;
    }

    const float4* vbase = (const float4*)(values + ((size_t)b * TT + t0) * DD);
    // row stride = D/4 = 256 float4

    float m = -INFINITY, l = 0.f;
    float ctx[16];
#pragma unroll
    for (int k = 0; k < 16; k++) ctx[k] = 0.f;

    // two rows in flight
    float4 cur0[4], cur1[4];
#pragma unroll
    for (int g = 0; g < 4; g++) {
        cur0[g] = vbase[g * 64 + lane];
        cur1[g] = vbase[256 + g * 64 + lane];
    }

    for (int r = 0; r < TCHUNK; r += 2) {
        float4 nxt0[4], nxt1[4];
        const bool have_next = (r + 2 < TCHUNK);
        if (have_next) {
#pragma unroll
            for (int g = 0; g < 4; g++) {
                nxt0[g] = vbase[(size_t)(r + 2) * 256 + g * 64 + lane];
                nxt1[g] = vbase[(size_t)(r + 3) * 256 + g * 64 + lane];
            }
        }
        float vf0[16], vf1[16];
#pragma unroll
        for (int g = 0; g < 4; g++) {
            vf0[4 * g + 0] = cur0[g].x; vf0[4 * g + 1] = cur0[g].y;
            vf0[4 * g + 2] = cur0[g].z; vf0[4 * g + 3] = cur0[g].w;
            vf1[4 * g + 0] = cur1[g].x; vf1[4 * g + 1] = cur1[g].y;
            vf1[4 * g + 2] = cur1[g].z; vf1[4 * g + 3] = cur1[g].w;
        }

        float s0 = 0.f, s1 = 0.f;
#pragma unroll
        for (int k = 0; k < 16; k++) {
            s0 = fmaf(qf[k], vf0[k], s0);
            s1 = fmaf(qf[k], vf1[k], s1);
        }
        // two independent butterfly chains -> latency overlaps
#pragma unroll
        for (int off = 32; off >= 1; off >>= 1) {
            s0 += __shfl_xor(s0, off, 64);
            s1 += __shfl_xor(s1, off, 64);
        }

        // online softmax update row r (s, m wave-uniform -> uniform branch)
        if (s0 <= m) {
            float p = __expf(s0 - m);
            l += p;
#pragma unroll
            for (int k = 0; k < 16; k++) ctx[k] = fmaf(p, vf0[k], ctx[k]);
        } else {
            float corr = __expf(m - s0);   // exp(-inf)=0 on first row
            m = s0;
            l = fmaf(l, corr, 1.f);
#pragma unroll
            for (int k = 0; k < 16; k++) ctx[k] = fmaf(ctx[k], corr, vf0[k]);
        }
        // row r+1
        if (s1 <= m) {
            float p = __expf(s1 - m);
            l += p;
#pragma unroll
            for (int k = 0; k < 16; k++) ctx[k] = fmaf(p, vf1[k], ctx[k]);
        } else {
            float corr = __expf(m - s1);
            m = s1;
            l = fmaf(l, corr, 1.f);
#pragma unroll
            for (int k = 0; k < 16; k++) ctx[k] = fmaf(ctx[k], corr, vf1[k]);
        }

        if (lane == 0) {
            float2* sp = (float2*)(scores + (size_t)b * TT + t0 + r);
            *sp = make_float2(s0, s1);
        }
        if (have_next) {
#pragma unroll
            for (int g = 0; g < 4; g++) { cur0[g] = nxt0[g]; cur1[g] = nxt1[g]; }
        }
    }

    const int ci = b * NC + chunk;
    if (lane == 0) { pm[ci] = m; pl[ci] = l; }
    float4* pc = (float4*)(pctx + (size_t)ci * DD);
#pragma unroll
    for (int g = 0; g < 4; g++)
        pc[g * 64 + lane] = make_float4(ctx[4 * g + 0], ctx[4 * g + 1],
                                        ctx[4 * g + 2], ctx[4 * g + 3]);
}

__global__ __launch_bounds__(256) void attn_pass2(
    const float* __restrict__ ws,
    float* __restrict__ out) {
    const float* scores = ws;
    const float* pm = ws + BB * TT;
    const float* pl = pm + BB * NC;
    const float* pctx = pl + BB * NC;

    const int tid   = threadIdx.x;
    const int b     = blockIdx.x >> 2;
    const int slice = blockIdx.x & 3;

    __shared__ float s_e[NC];
    __shared__ float s_M, s_L;
    if (tid < 64) {  // wave 0: reduce the 64 chunk partials
        float mi = pm[b * NC + tid];
        float li = pl[b * NC + tid];
        float M = mi;
#pragma unroll
        for (int off = 32; off >= 1; off >>= 1) M = fmaxf(M, __shfl_xor(M, off, 64));
        float e  = __expf(mi - M);
        float lw = li * e;
#pragma unroll
        for (int off = 32; off >= 1; off >>= 1) lw += __shfl_xor(lw, off, 64);
        s_e[tid] = e;
        if (tid == 0) { s_M = M; s_L = lw; }
    }
    __syncthreads();
    const float M  = s_M;
    const float rL = 1.0f / s_L;

    // context slice: d = slice*256 + tid
    const int d = slice * 256 + tid;
    const float* base = pctx + (size_t)b * NC * DD + d;
    float acc = 0.f;
#pragma unroll 8
    for (int i = 0; i < NC; i++) acc = fmaf(base[(size_t)i * DD], s_e[i], acc);
    out[(size_t)b * DD + d] = acc * rL;

    // weights: t = slice*512 + k*256 + tid
    float* wout = out + BB * DD;
#pragma unroll
    for (int k = 0; k < 2; k++) {
        int t = slice * 512 + k * 256 + tid;
        float w = __expf(scores[(size_t)b * TT + t] - M) * rL;
        wout[(size_t)b * TT + t] = w;
    }
}

extern "C" void kernel_launch(void* const* d_in, const int* in_sizes, int n_in,
                              void* d_out, int out_size, void* d_ws, size_t ws_size,
                              hipStream_t stream) {
    const float* query  = (const float*)d_in[0];
    const float* values = (const float*)d_in[1];
    float* ws = (float*)d_ws;
    float* out = (float*)d_out;

    attn_pass1<<<dim3(BB * BLOCKS_PER_B), dim3(256), 0, stream>>>(query, values, ws);
    attn_pass2<<<dim3(BB * 4), dim3(256), 0, stream>>>(ws, out);
}